// Round 1
// baseline (599.161 us; speedup 1.0000x reference)
//
#include <hip/hip_runtime.h>

// Causal linear attention (chunked scan), fp32 throughout.
// q = softmax(x Wq^T) per head; k = softmax(x Wk^T); v = x Wv^T
// out[t] = q_t @ (sum_{s<=t} k_s^T v_s)
//        = q_t @ S_prev(chunk) + sum_{s in chunk, s<=t} (q_t . k_s) v_s

constexpr int DIM  = 1024;
constexpr int H    = 16;
constexpr int DH   = 64;
constexpr int LSEQ = 2048;
constexpr int NB   = 2;
constexpr int MTOK = NB * LSEQ;   // 4096 tokens
constexpr int CS   = 64;          // chunk size
constexpr int NC   = LSEQ / CS;   // 32 chunks

// ---------------- GEMM NT: C[m][n] = sum_k A[m][k] * W[n][k] ----------------
// BM=128, BN=64, BK=16, 256 threads, 8x4 microtile.
constexpr int BM = 128, BN = 64, BK = 16;

__global__ __launch_bounds__(256) void gemm_nt(const float* __restrict__ A,
                                               const float* __restrict__ W,
                                               float* __restrict__ C) {
  __shared__ float As[BK][BM + 4];   // [k][m], pad keeps 16B alignment
  __shared__ float Ws[BK][BN + 4];   // [k][n]
  const int bm = blockIdx.y * BM;
  const int bn = blockIdx.x * BN;
  const int tid = threadIdx.x;
  const int tx = tid & 15;   // n-dir, 4 cols each
  const int ty = tid >> 4;   // m-dir, 8 rows each

  float acc[8][4];
#pragma unroll
  for (int i = 0; i < 8; i++)
#pragma unroll
    for (int j = 0; j < 4; j++) acc[i][j] = 0.f;

  const int lrow = tid >> 2;   // 0..63
  const int lc4  = tid & 3;    // which float4 of the 16-wide k slice

  for (int k0 = 0; k0 < DIM; k0 += BK) {
    // A tile: 128 rows x 16 k = 512 float4, 2 per thread
#pragma unroll
    for (int i = 0; i < 2; i++) {
      const int row = lrow + i * 64;
      const float4 av = *(const float4*)&A[(size_t)(bm + row) * DIM + k0 + lc4 * 4];
      As[lc4 * 4 + 0][row] = av.x;
      As[lc4 * 4 + 1][row] = av.y;
      As[lc4 * 4 + 2][row] = av.z;
      As[lc4 * 4 + 3][row] = av.w;
    }
    // W tile: 64 rows x 16 k = 256 float4, 1 per thread
    {
      const int row = lrow;
      const float4 wv = *(const float4*)&W[(size_t)(bn + row) * DIM + k0 + lc4 * 4];
      Ws[lc4 * 4 + 0][row] = wv.x;
      Ws[lc4 * 4 + 1][row] = wv.y;
      Ws[lc4 * 4 + 2][row] = wv.z;
      Ws[lc4 * 4 + 3][row] = wv.w;
    }
    __syncthreads();
#pragma unroll
    for (int k = 0; k < BK; k++) {
      float a[8], b[4];
      *(float4*)&a[0] = *(const float4*)&As[k][ty * 8];
      *(float4*)&a[4] = *(const float4*)&As[k][ty * 8 + 4];
      *(float4*)&b[0] = *(const float4*)&Ws[k][tx * 4];
#pragma unroll
      for (int i = 0; i < 8; i++)
#pragma unroll
        for (int j = 0; j < 4; j++) acc[i][j] = fmaf(a[i], b[j], acc[i][j]);
    }
    __syncthreads();
  }
#pragma unroll
  for (int i = 0; i < 8; i++) {
    float4 o = make_float4(acc[i][0], acc[i][1], acc[i][2], acc[i][3]);
    *(float4*)&C[(size_t)(bm + ty * 8 + i) * DIM + bn + tx * 4] = o;
  }
}

// ---------------- per-head softmax over 64 contiguous elements --------------
__global__ __launch_bounds__(256) void softmax_heads(float* __restrict__ x) {
  const int lane = threadIdx.x & 63;
  const int wid  = threadIdx.x >> 6;
  const size_t g = (size_t)blockIdx.x * 4 + wid;   // group index, groups of 64
  float v = x[g * 64 + lane];
  float m = v;
#pragma unroll
  for (int o = 32; o > 0; o >>= 1) m = fmaxf(m, __shfl_xor(m, o, 64));
  const float e = __expf(v - m);
  float s = e;
#pragma unroll
  for (int o = 32; o > 0; o >>= 1) s += __shfl_xor(s, o, 64);
  x[g * 64 + lane] = e / s;
}

// ---------------- pass A: per-chunk S_c = K_c^T V_c (64x64) -----------------
__global__ __launch_bounds__(256) void chunk_kv_sums(const float* __restrict__ kp,
                                                     const float* __restrict__ vp,
                                                     float* __restrict__ cs) {
  __shared__ float Ks[CS][DH];   // [t][i]
  __shared__ float Vs[CS][DH];   // [t][j]
  const int c = blockIdx.x, h = blockIdx.y, n = blockIdx.z;
  const int tid = threadIdx.x;
  const size_t gbase = ((size_t)(n * LSEQ + c * CS)) * DIM + h * DH;
#pragma unroll
  for (int i = 0; i < 4; i++) {
    const int f = tid + i * 256;   // 1024 float4s (64x64 each for K and V)
    const int t = f >> 4, d4 = f & 15;
    *(float4*)&Ks[t][d4 * 4] = *(const float4*)&kp[gbase + (size_t)t * DIM + d4 * 4];
    *(float4*)&Vs[t][d4 * 4] = *(const float4*)&vp[gbase + (size_t)t * DIM + d4 * 4];
  }
  __syncthreads();
  const int tx = tid & 15, ty = tid >> 4;
  float acc[4][4];
#pragma unroll
  for (int i = 0; i < 4; i++)
#pragma unroll
    for (int j = 0; j < 4; j++) acc[i][j] = 0.f;
  for (int t = 0; t < CS; t++) {
    float kv[4], vv[4];
    *(float4*)kv = *(const float4*)&Ks[t][ty * 4];
    *(float4*)vv = *(const float4*)&Vs[t][tx * 4];
#pragma unroll
    for (int i = 0; i < 4; i++)
#pragma unroll
      for (int j = 0; j < 4; j++) acc[i][j] = fmaf(kv[i], vv[j], acc[i][j]);
  }
  float* outp = cs + ((size_t)((n * H + h) * NC + c)) * (DH * DH);
#pragma unroll
  for (int i = 0; i < 4; i++) {
    float4 o = make_float4(acc[i][0], acc[i][1], acc[i][2], acc[i][3]);
    *(float4*)&outp[(size_t)(ty * 4 + i) * DH + tx * 4] = o;
  }
}

// ------- pass B: in-place exclusive prefix over chunks, per (n,h) -----------
__global__ __launch_bounds__(256) void prefix_chunks(float* __restrict__ cs) {
  const int nh = blockIdx.x;   // 32
  float4* base = (float4*)(cs + (size_t)nh * NC * (DH * DH));
  const int tid = threadIdx.x;
  float4 run[4];
#pragma unroll
  for (int i = 0; i < 4; i++) run[i] = make_float4(0.f, 0.f, 0.f, 0.f);
  for (int c = 0; c < NC; c++) {
    float4* p = base + (size_t)c * (DH * DH / 4);
#pragma unroll
    for (int i = 0; i < 4; i++) {
      const float4 cur = p[tid + i * 256];
      p[tid + i * 256] = run[i];
      run[i].x += cur.x; run[i].y += cur.y; run[i].z += cur.z; run[i].w += cur.w;
    }
  }
}

// ---- pass C: out = Q @ S_prev + tril(Q K^T) @ V per chunk ------------------
__global__ __launch_bounds__(256) void attn_out(const float* __restrict__ qp,
                                                const float* __restrict__ kp,
                                                const float* __restrict__ vp,
                                                const float* __restrict__ cs,
                                                float* __restrict__ out) {
  __shared__ float Qst[DH][CS + 4];   // [i][t] transposed, pad keeps b128 align
  __shared__ float Kst[DH][CS + 4];   // [i][s]
  __shared__ float Vs[CS][DH];        // [s][j]
  __shared__ float Sp[DH][DH];        // exclusive-prefix state [i][j]
  __shared__ float Pst[CS][CS + 4];   // masked P^T: [s][t]
  const int c = blockIdx.x, h = blockIdx.y, n = blockIdx.z;
  const int tid = threadIdx.x;
  const int tx = tid & 15, ty = tid >> 4;
  const size_t gbase = ((size_t)(n * LSEQ + c * CS)) * DIM + h * DH;

#pragma unroll
  for (int i = 0; i < 4; i++) {
    const int f = tid + i * 256;
    const int t = f >> 4, d4 = f & 15;
    const float4 qv = *(const float4*)&qp[gbase + (size_t)t * DIM + d4 * 4];
    const float4 kv = *(const float4*)&kp[gbase + (size_t)t * DIM + d4 * 4];
    const float4 vv = *(const float4*)&vp[gbase + (size_t)t * DIM + d4 * 4];
    Qst[d4 * 4 + 0][t] = qv.x; Qst[d4 * 4 + 1][t] = qv.y;
    Qst[d4 * 4 + 2][t] = qv.z; Qst[d4 * 4 + 3][t] = qv.w;
    Kst[d4 * 4 + 0][t] = kv.x; Kst[d4 * 4 + 1][t] = kv.y;
    Kst[d4 * 4 + 2][t] = kv.z; Kst[d4 * 4 + 3][t] = kv.w;
    *(float4*)&Vs[t][d4 * 4] = vv;
  }
  const float4* spg = (const float4*)(cs + ((size_t)((n * H + h) * NC + c)) * (DH * DH));
#pragma unroll
  for (int i = 0; i < 4; i++) ((float4*)&Sp[0][0])[tid + i * 256] = spg[tid + i * 256];
  __syncthreads();

  // phase 1: P[t][s] = q_t . k_s, masked to s<=t, stored transposed Pst[s][t]
  {
    float pacc[4][4];
#pragma unroll
    for (int i = 0; i < 4; i++)
#pragma unroll
      for (int j = 0; j < 4; j++) pacc[i][j] = 0.f;
    for (int i = 0; i < DH; i++) {
      float a[4], b[4];
      *(float4*)a = *(const float4*)&Qst[i][ty * 4];
      *(float4*)b = *(const float4*)&Kst[i][tx * 4];
#pragma unroll
      for (int ii = 0; ii < 4; ii++)
#pragma unroll
        for (int jj = 0; jj < 4; jj++) pacc[ii][jj] = fmaf(a[ii], b[jj], pacc[ii][jj]);
    }
#pragma unroll
    for (int ii = 0; ii < 4; ii++)
#pragma unroll
      for (int jj = 0; jj < 4; jj++) {
        const int t = ty * 4 + ii, s = tx * 4 + jj;
        Pst[s][t] = (s <= t) ? pacc[ii][jj] : 0.f;
      }
  }
  __syncthreads();

  // phase 2: out[t][j] = sum_i Q[t][i]*Sp[i][j] + sum_s Pst[s][t]*Vs[s][j]
  float oacc[4][4];
#pragma unroll
  for (int i = 0; i < 4; i++)
#pragma unroll
    for (int j = 0; j < 4; j++) oacc[i][j] = 0.f;
  for (int i = 0; i < DH; i++) {
    float a[4], b[4];
    *(float4*)a = *(const float4*)&Qst[i][ty * 4];
    *(float4*)b = *(const float4*)&Sp[i][tx * 4];
#pragma unroll
    for (int ii = 0; ii < 4; ii++)
#pragma unroll
      for (int jj = 0; jj < 4; jj++) oacc[ii][jj] = fmaf(a[ii], b[jj], oacc[ii][jj]);
  }
  for (int s = 0; s < CS; s++) {
    float a[4], b[4];
    *(float4*)a = *(const float4*)&Pst[s][ty * 4];
    *(float4*)b = *(const float4*)&Vs[s][tx * 4];
#pragma unroll
    for (int ii = 0; ii < 4; ii++)
#pragma unroll
      for (int jj = 0; jj < 4; jj++) oacc[ii][jj] = fmaf(a[ii], b[jj], oacc[ii][jj]);
  }
#pragma unroll
  for (int ii = 0; ii < 4; ii++) {
    float4 o = make_float4(oacc[ii][0], oacc[ii][1], oacc[ii][2], oacc[ii][3]);
    *(float4*)&out[gbase + (size_t)(ty * 4 + ii) * DIM + tx * 4] = o;
  }
}

extern "C" void kernel_launch(void* const* d_in, const int* in_sizes, int n_in,
                              void* d_out, int out_size, void* d_ws, size_t ws_size,
                              hipStream_t stream) {
  const float* query = (const float*)d_in[0];
  const float* key   = (const float*)d_in[1];
  const float* Wq    = (const float*)d_in[2];
  const float* Wk    = (const float*)d_in[3];
  const float* Wv    = (const float*)d_in[4];
  float* out = (float*)d_out;

  // workspace carve-up (all 16B aligned)
  const size_t proj_elems = (size_t)MTOK * DIM;           // 4 Mi floats each
  float* qp = (float*)d_ws;
  float* kp = qp + proj_elems;
  float* vp = kp + proj_elems;
  float* cs = vp + proj_elems;                            // NB*H*NC*64*64 floats

  const dim3 gblk(256);
  const dim3 ggrid(DIM / BN, MTOK / BM);                  // (16, 32)
  gemm_nt<<<ggrid, gblk, 0, stream>>>(query, Wq, qp);
  gemm_nt<<<ggrid, gblk, 0, stream>>>(key,   Wk, kp);
  gemm_nt<<<ggrid, gblk, 0, stream>>>(key,   Wv, vp);

  const int ngroups = MTOK * H;                           // 65536 softmax rows
  softmax_heads<<<dim3(ngroups / 4), gblk, 0, stream>>>(qp);
  softmax_heads<<<dim3(ngroups / 4), gblk, 0, stream>>>(kp);

  chunk_kv_sums<<<dim3(NC, H, NB), gblk, 0, stream>>>(kp, vp, cs);
  prefix_chunks<<<dim3(NB * H), gblk, 0, stream>>>(cs);
  attn_out<<<dim3(NC, H, NB), gblk, 0, stream>>>(qp, kp, vp, cs, out);
}

// Round 3
// 243.763 us; speedup vs baseline: 2.4580x; 2.4580x over previous
//
#include <hip/hip_runtime.h>

// Causal linear attention (chunked scan).
// Projections q/k/v via bf16 MFMA GEMM (fp32 accumulate) with fused per-head
// softmax epilogue; attention passes in fp32.

constexpr int DIM  = 1024;
constexpr int H    = 16;
constexpr int DH   = 64;
constexpr int LSEQ = 2048;
constexpr int NB   = 2;
constexpr int MTOK = NB * LSEQ;   // 4096 tokens
constexpr int CS   = 64;          // chunk size
constexpr int NC   = LSEQ / CS;   // 32 chunks

typedef __bf16 bf16x8 __attribute__((ext_vector_type(8)));
typedef float floatx4 __attribute__((ext_vector_type(4)));

__device__ __forceinline__ unsigned short f2bf(float f) {
  unsigned int u = __float_as_uint(f);
  u += 0x7FFFu + ((u >> 16) & 1u);   // round-to-nearest-even
  return (unsigned short)(u >> 16);
}

__device__ __forceinline__ void async16(void* lds, const void* g) {
  __builtin_amdgcn_global_load_lds(
      (const __attribute__((address_space(1))) unsigned int*)g,
      (__attribute__((address_space(3))) unsigned int*)lds, 16, 0, 0);
}

// ------------- cast fp32 -> bf16 for query/key and the three weights --------
__global__ __launch_bounds__(256) void cast_all(const float* __restrict__ q,
                                                const float* __restrict__ k,
                                                const float* __restrict__ wq,
                                                const float* __restrict__ wk,
                                                const float* __restrict__ wv,
                                                unsigned short* __restrict__ xbf,
                                                unsigned short* __restrict__ wbf) {
  const int seg = blockIdx.y;
  const float* src;
  unsigned short* dst;
  int n4;
  if (seg == 0)      { src = q;  dst = xbf;                  n4 = (4 << 20) / 4; }
  else if (seg == 1) { src = k;  dst = xbf + (4 << 20);      n4 = (4 << 20) / 4; }
  else if (seg == 2) { src = wq; dst = wbf;                  n4 = (1 << 20) / 4; }
  else if (seg == 3) { src = wk; dst = wbf + (1 << 20);      n4 = (1 << 20) / 4; }
  else               { src = wv; dst = wbf + (2 << 20);      n4 = (1 << 20) / 4; }
  for (int i = blockIdx.x * 256 + threadIdx.x; i < n4; i += gridDim.x * 256) {
    const float4 f = ((const float4*)src)[i];
    ((ushort4*)dst)[i] = make_ushort4(f2bf(f.x), f2bf(f.y), f2bf(f.z), f2bf(f.w));
  }
}

// ------------- bf16 MFMA GEMM NT: C[m][n] = sum_k A[m][k]*W[n][k] -----------
// Tile 128(M) x 64(N), BK=32, 256 threads = 4 waves, wave -> 64x32 (4x2 MFMA).
// One 16x16x32 MFMA consumes the FULL BK=32 slice (k = quad*8 + j).
// N-tile 64 == one head => fused per-head softmax epilogue (do_softmax).
__global__ __launch_bounds__(256) void gemm_bf16(const unsigned short* __restrict__ A,
                                                 const unsigned short* __restrict__ W,
                                                 float* __restrict__ C,
                                                 int do_softmax) {
  __shared__ unsigned short As[128 * 32];   // [m][k] row-major
  __shared__ unsigned short Ws[64 * 32];    // [n][k] row-major
  __shared__ float Cs[128][68];             // +4 pad for epilogue banks

  const int tid  = threadIdx.x;
  const int bn   = blockIdx.x * 64;
  const int bm   = blockIdx.y * 128;
  const int lane = tid & 63;
  const int wid  = tid >> 6;
  const int wm   = wid >> 1, wn = wid & 1;
  const int row16 = lane & 15, quad = lane >> 4;

  floatx4 acc[4][2] = {};

  // staging addresses: flat f -> row=f>>2, 16B-chunk=f&3; LDS off = f*16B
  const unsigned short* gA0 = A + (size_t)(bm + (tid >> 2)) * DIM + (tid & 3) * 8;
  const unsigned short* gA1 = A + (size_t)(bm + 64 + (tid >> 2)) * DIM + (tid & 3) * 8;
  const unsigned short* gW  = W + (size_t)(bn + (tid >> 2)) * DIM + (tid & 3) * 8;
  unsigned short* lA0 = As + tid * 8;
  unsigned short* lA1 = As + (tid + 256) * 8;
  unsigned short* lW  = Ws + tid * 8;

  for (int k0 = 0; k0 < DIM; k0 += 32) {
    __syncthreads();
    async16(lA0, gA0 + k0);
    async16(lA1, gA1 + k0);
    async16(lW,  gW  + k0);
    __syncthreads();
    bf16x8 a[4], b[2];
#pragma unroll
    for (int mt = 0; mt < 4; mt++)
      a[mt] = *(const bf16x8*)&As[(wm * 64 + mt * 16 + row16) * 32 + quad * 8];
#pragma unroll
    for (int nt = 0; nt < 2; nt++)
      b[nt] = *(const bf16x8*)&Ws[(wn * 32 + nt * 16 + row16) * 32 + quad * 8];
#pragma unroll
    for (int mt = 0; mt < 4; mt++)
#pragma unroll
      for (int nt = 0; nt < 2; nt++)
        acc[mt][nt] = __builtin_amdgcn_mfma_f32_16x16x32_bf16(a[mt], b[nt], acc[mt][nt], 0, 0, 0);
  }

  __syncthreads();
  // C/D layout: col = lane&15, row = quad*4 + reg  [verified m89/m91]
#pragma unroll
  for (int mt = 0; mt < 4; mt++)
#pragma unroll
    for (int nt = 0; nt < 2; nt++)
#pragma unroll
      for (int r = 0; r < 4; r++)
        Cs[wm * 64 + mt * 16 + quad * 4 + r][wn * 32 + nt * 16 + row16] = acc[mt][nt][r];
  __syncthreads();

  // epilogue: wave handles 32 rows; 64 lanes <-> the head's 64 dims
  for (int r = 0; r < 32; r++) {
    const int row = wid * 32 + r;
    float v = Cs[row][lane];
    if (do_softmax) {
      float m = v;
#pragma unroll
      for (int o = 32; o > 0; o >>= 1) m = fmaxf(m, __shfl_xor(m, o, 64));
      const float e = __expf(v - m);
      float s = e;
#pragma unroll
      for (int o = 32; o > 0; o >>= 1) s += __shfl_xor(s, o, 64);
      v = e / s;
    }
    C[(size_t)(bm + row) * DIM + bn + lane] = v;
  }
}

// ---------------- pass A: per-chunk S_c = K_c^T V_c (64x64) -----------------
__global__ __launch_bounds__(256) void chunk_kv_sums(const float* __restrict__ kp,
                                                     const float* __restrict__ vp,
                                                     float* __restrict__ cs) {
  __shared__ float Ks[CS][DH];
  __shared__ float Vs[CS][DH];
  const int c = blockIdx.x, h = blockIdx.y, n = blockIdx.z;
  const int tid = threadIdx.x;
  const size_t gbase = ((size_t)(n * LSEQ + c * CS)) * DIM + h * DH;
#pragma unroll
  for (int i = 0; i < 4; i++) {
    const int f = tid + i * 256;
    const int t = f >> 4, d4 = f & 15;
    *(float4*)&Ks[t][d4 * 4] = *(const float4*)&kp[gbase + (size_t)t * DIM + d4 * 4];
    *(float4*)&Vs[t][d4 * 4] = *(const float4*)&vp[gbase + (size_t)t * DIM + d4 * 4];
  }
  __syncthreads();
  const int tx = tid & 15, ty = tid >> 4;
  float acc[4][4];
#pragma unroll
  for (int i = 0; i < 4; i++)
#pragma unroll
    for (int j = 0; j < 4; j++) acc[i][j] = 0.f;
  for (int t = 0; t < CS; t++) {
    float kv[4], vv[4];
    *(float4*)kv = *(const float4*)&Ks[t][ty * 4];
    *(float4*)vv = *(const float4*)&Vs[t][tx * 4];
#pragma unroll
    for (int i = 0; i < 4; i++)
#pragma unroll
      for (int j = 0; j < 4; j++) acc[i][j] = fmaf(kv[i], vv[j], acc[i][j]);
  }
  float* outp = cs + ((size_t)((n * H + h) * NC + c)) * (DH * DH);
#pragma unroll
  for (int i = 0; i < 4; i++) {
    float4 o = make_float4(acc[i][0], acc[i][1], acc[i][2], acc[i][3]);
    *(float4*)&outp[(size_t)(ty * 4 + i) * DH + tx * 4] = o;
  }
}

// ------- pass B: exclusive prefix over chunks, entry-parallel ---------------
__global__ __launch_bounds__(256) void prefix_chunks(float* __restrict__ cs) {
  const int nh = blockIdx.x >> 4;
  const int e  = (blockIdx.x & 15) * 256 + threadIdx.x;   // 0..4095
  float* base = cs + (size_t)nh * NC * (DH * DH) + e;
  float vals[NC];
#pragma unroll
  for (int c = 0; c < NC; c++) vals[c] = base[(size_t)c * (DH * DH)];
  float run = 0.f;
#pragma unroll
  for (int c = 0; c < NC; c++) {
    const float cur = vals[c];
    base[(size_t)c * (DH * DH)] = run;
    run += cur;
  }
}

// ---- pass C: out = Q @ S_prev + tril(Q K^T) @ V per chunk ------------------
__global__ __launch_bounds__(256) void attn_out(const float* __restrict__ qp,
                                                const float* __restrict__ kp,
                                                const float* __restrict__ vp,
                                                const float* __restrict__ cs,
                                                float* __restrict__ out) {
  __shared__ float Qst[DH][CS + 4];
  __shared__ float Kst[DH][CS + 4];
  __shared__ float Vs[CS][DH];
  __shared__ float Sp[DH][DH];
  __shared__ float Pst[CS][CS + 4];
  const int c = blockIdx.x, h = blockIdx.y, n = blockIdx.z;
  const int tid = threadIdx.x;
  const int tx = tid & 15, ty = tid >> 4;
  const size_t gbase = ((size_t)(n * LSEQ + c * CS)) * DIM + h * DH;

#pragma unroll
  for (int i = 0; i < 4; i++) {
    const int f = tid + i * 256;
    const int t = f >> 4, d4 = f & 15;
    const float4 qv = *(const float4*)&qp[gbase + (size_t)t * DIM + d4 * 4];
    const float4 kv = *(const float4*)&kp[gbase + (size_t)t * DIM + d4 * 4];
    const float4 vv = *(const float4*)&vp[gbase + (size_t)t * DIM + d4 * 4];
    Qst[d4 * 4 + 0][t] = qv.x; Qst[d4 * 4 + 1][t] = qv.y;
    Qst[d4 * 4 + 2][t] = qv.z; Qst[d4 * 4 + 3][t] = qv.w;
    Kst[d4 * 4 + 0][t] = kv.x; Kst[d4 * 4 + 1][t] = kv.y;
    Kst[d4 * 4 + 2][t] = kv.z; Kst[d4 * 4 + 3][t] = kv.w;
    *(float4*)&Vs[t][d4 * 4] = vv;
  }
  const float4* spg = (const float4*)(cs + ((size_t)((n * H + h) * NC + c)) * (DH * DH));
#pragma unroll
  for (int i = 0; i < 4; i++) ((float4*)&Sp[0][0])[tid + i * 256] = spg[tid + i * 256];
  __syncthreads();

  {
    float pacc[4][4];
#pragma unroll
    for (int i = 0; i < 4; i++)
#pragma unroll
      for (int j = 0; j < 4; j++) pacc[i][j] = 0.f;
    for (int i = 0; i < DH; i++) {
      float a[4], b[4];
      *(float4*)a = *(const float4*)&Qst[i][ty * 4];
      *(float4*)b = *(const float4*)&Kst[i][tx * 4];
#pragma unroll
      for (int ii = 0; ii < 4; ii++)
#pragma unroll
        for (int jj = 0; jj < 4; jj++) pacc[ii][jj] = fmaf(a[ii], b[jj], pacc[ii][jj]);
    }
#pragma unroll
    for (int ii = 0; ii < 4; ii++)
#pragma unroll
      for (int jj = 0; jj < 4; jj++) {
        const int t = ty * 4 + ii, s = tx * 4 + jj;
        Pst[s][t] = (s <= t) ? pacc[ii][jj] : 0.f;
      }
  }
  __syncthreads();

  float oacc[4][4];
#pragma unroll
  for (int i = 0; i < 4; i++)
#pragma unroll
    for (int j = 0; j < 4; j++) oacc[i][j] = 0.f;
  for (int i = 0; i < DH; i++) {
    float a[4], b[4];
    *(float4*)a = *(const float4*)&Qst[i][ty * 4];
    *(float4*)b = *(const float4*)&Sp[i][tx * 4];
#pragma unroll
    for (int ii = 0; ii < 4; ii++)
#pragma unroll
      for (int jj = 0; jj < 4; jj++) oacc[ii][jj] = fmaf(a[ii], b[jj], oacc[ii][jj]);
  }
  for (int s = 0; s < CS; s++) {
    float a[4], b[4];
    *(float4*)a = *(const float4*)&Pst[s][ty * 4];
    *(float4*)b = *(const float4*)&Vs[s][tx * 4];
#pragma unroll
    for (int ii = 0; ii < 4; ii++)
#pragma unroll
      for (int jj = 0; jj < 4; jj++) oacc[ii][jj] = fmaf(a[ii], b[jj], oacc[ii][jj]);
  }
#pragma unroll
  for (int ii = 0; ii < 4; ii++) {
    float4 o = make_float4(oacc[ii][0], oacc[ii][1], oacc[ii][2], oacc[ii][3]);
    *(float4*)&out[gbase + (size_t)(ty * 4 + ii) * DIM + tx * 4] = o;
  }
}

extern "C" void kernel_launch(void* const* d_in, const int* in_sizes, int n_in,
                              void* d_out, int out_size, void* d_ws, size_t ws_size,
                              hipStream_t stream) {
  const float* query = (const float*)d_in[0];
  const float* key   = (const float*)d_in[1];
  const float* Wq    = (const float*)d_in[2];
  const float* Wk    = (const float*)d_in[3];
  const float* Wv    = (const float*)d_in[4];
  float* out = (float*)d_out;

  // d_ws: [qp 4M f32][kp 4M][vp 4M][cs 4M f32]  = 64 MB total (round-1 proven)
  // bf16 x staging overlays cs; bf16 weights overlay d_out (dead until attn_out)
  const size_t PM = (size_t)4 << 20;
  float* qp = (float*)d_ws;
  float* kp = qp + PM;
  float* vp = kp + PM;
  float* cs = vp + PM;                               // 4M floats (=NB*H*NC*64*64)
  unsigned short* xbf = (unsigned short*)cs;         // 8M bf16 (query,key)
  unsigned short* wbf = (unsigned short*)out;        // 3M bf16 weights in d_out

  cast_all<<<dim3(512, 5), 256, 0, stream>>>(query, key, Wq, Wk, Wv, xbf, wbf);

  const dim3 ggrid(DIM / 64, MTOK / 128);            // (16, 32) = 512 blocks
  gemm_bf16<<<ggrid, 256, 0, stream>>>(xbf,              wbf,             qp, 1);
  gemm_bf16<<<ggrid, 256, 0, stream>>>(xbf + (4 << 20),  wbf + (1 << 20), kp, 1);
  gemm_bf16<<<ggrid, 256, 0, stream>>>(xbf + (4 << 20),  wbf + (2 << 20), vp, 0);

  chunk_kv_sums<<<dim3(NC, H, NB), 256, 0, stream>>>(kp, vp, cs);
  prefix_chunks<<<dim3(NB * H * 16), 256, 0, stream>>>(cs);
  attn_out<<<dim3(NC, H, NB), 256, 0, stream>>>(qp, kp, vp, cs, out);
}

// Round 4
// 206.030 us; speedup vs baseline: 2.9081x; 1.1831x over previous
//
#include <hip/hip_runtime.h>

// Causal linear attention (chunked scan), bf16 MFMA end-to-end.
// q = softmax(x Wq^T), k = softmax(x Wk^T), v = x Wv^T   (bf16 MFMA GEMMs)
// T_c = sum_{t in chunk} v_t^T (x) k_t  (= S_c^T)        (MFMA, pass A)
// Tpre = exclusive prefix of T_c over chunks (fp32 scan -> bf16)  (pass B)
// out = Q @ Tpre^T + tril(Q K^T) @ V                     (MFMA, pass C)

constexpr int DIM  = 1024;
constexpr int H    = 16;
constexpr int DH   = 64;
constexpr int LSEQ = 2048;
constexpr int NB   = 2;
constexpr int MTOK = NB * LSEQ;   // 4096 tokens
constexpr int CS   = 64;          // chunk size
constexpr int NC   = LSEQ / CS;   // 32 chunks

typedef __bf16 bf16x8 __attribute__((ext_vector_type(8)));
typedef float floatx4 __attribute__((ext_vector_type(4)));
typedef unsigned short ushort_t;

__device__ __forceinline__ ushort_t f2bf(float f) {
  unsigned int u = __float_as_uint(f);
  u += 0x7FFFu + ((u >> 16) & 1u);   // RTNE
  return (ushort_t)(u >> 16);
}
__device__ __forceinline__ float bf2f(ushort_t b) {
  return __uint_as_float(((unsigned int)b) << 16);
}

__device__ __forceinline__ void async16(void* lds, const void* g) {
  __builtin_amdgcn_global_load_lds(
      (const __attribute__((address_space(1))) unsigned int*)g,
      (__attribute__((address_space(3))) unsigned int*)lds, 16, 0, 0);
}

// read a bf16x8 fragment from a transposed stride-33-uint LDS array
__device__ __forceinline__ bf16x8 tfrag(const unsigned int* T, int row, int uoff) {
  union { bf16x8 v; unsigned int u[4]; } r;
  const unsigned int* p = T + row * 33 + uoff;
  r.u[0] = p[0]; r.u[1] = p[1]; r.u[2] = p[2]; r.u[3] = p[3];
  return r.v;
}

// transpose a 64x64 bf16 tile (global, row stride DIM) into stride-33-uint LDS:
// TT[uint at row j, col tp] = (src[2tp][j], src[2tp+1][j]).  2-way banks = free.
__device__ __forceinline__ void transpose_tile(const ushort_t* g, unsigned int* TT, int tid) {
  const int ic = tid & 7, tp = tid >> 3;       // tp 0..31, ic 0..7
  const ushort_t* r0 = g + (size_t)(2 * tp) * DIM + ic * 8;
  union { uint4 q; ushort_t u[8]; } a0, a1;
  a0.q = *(const uint4*)r0;
  a1.q = *(const uint4*)(r0 + DIM);
#pragma unroll
  for (int j = 0; j < 8; j++)
    TT[(8 * ic + j) * 33 + tp] = (unsigned int)a0.u[j] | ((unsigned int)a1.u[j] << 16);
}

// ------------- cast fp32 -> bf16 for query/key and the three weights --------
__global__ __launch_bounds__(256) void cast_all(const float* __restrict__ q,
                                                const float* __restrict__ k,
                                                const float* __restrict__ wq,
                                                const float* __restrict__ wk,
                                                const float* __restrict__ wv,
                                                ushort_t* __restrict__ xbf,
                                                ushort_t* __restrict__ wbf) {
  const int seg = blockIdx.y;
  const float* src;
  ushort_t* dst;
  int n4;
  if (seg == 0)      { src = q;  dst = xbf;                  n4 = (4 << 20) / 4; }
  else if (seg == 1) { src = k;  dst = xbf + (4 << 20);      n4 = (4 << 20) / 4; }
  else if (seg == 2) { src = wq; dst = wbf;                  n4 = (1 << 20) / 4; }
  else if (seg == 3) { src = wk; dst = wbf + (1 << 20);      n4 = (1 << 20) / 4; }
  else               { src = wv; dst = wbf + (2 << 20);      n4 = (1 << 20) / 4; }
  for (int i = blockIdx.x * 256 + threadIdx.x; i < n4; i += gridDim.x * 256) {
    const float4 f = ((const float4*)src)[i];
    ((ushort4*)dst)[i] = make_ushort4(f2bf(f.x), f2bf(f.y), f2bf(f.z), f2bf(f.w));
  }
}

// ------------- bf16 MFMA GEMM NT, bf16 output, fused per-head softmax -------
// Tile 128(M) x 64(N), BK=32, 4 waves, wave -> 64x32 (4x2 MFMA).
__global__ __launch_bounds__(256) void gemm_bf16(const ushort_t* __restrict__ A,
                                                 const ushort_t* __restrict__ W,
                                                 ushort_t* __restrict__ C,
                                                 int do_softmax) {
  __shared__ ushort_t As[128 * 32];
  __shared__ ushort_t Ws[64 * 32];
  __shared__ ushort_t CsB[128 * 72];   // bf16 C tile, stride 72

  const int tid  = threadIdx.x;
  const int bn   = blockIdx.x * 64;
  const int bm   = blockIdx.y * 128;
  const int lane = tid & 63;
  const int wid  = tid >> 6;
  const int wm   = wid >> 1, wn = wid & 1;
  const int row16 = lane & 15, quad = lane >> 4;

  floatx4 acc[4][2] = {};

  const ushort_t* gA0 = A + (size_t)(bm + (tid >> 2)) * DIM + (tid & 3) * 8;
  const ushort_t* gA1 = A + (size_t)(bm + 64 + (tid >> 2)) * DIM + (tid & 3) * 8;
  const ushort_t* gW  = W + (size_t)(bn + (tid >> 2)) * DIM + (tid & 3) * 8;
  ushort_t* lA0 = As + tid * 8;
  ushort_t* lA1 = As + (tid + 256) * 8;
  ushort_t* lW  = Ws + tid * 8;

  for (int k0 = 0; k0 < DIM; k0 += 32) {
    __syncthreads();
    async16(lA0, gA0 + k0);
    async16(lA1, gA1 + k0);
    async16(lW,  gW  + k0);
    __syncthreads();
    bf16x8 a[4], b[2];
#pragma unroll
    for (int mt = 0; mt < 4; mt++)
      a[mt] = *(const bf16x8*)&As[(wm * 64 + mt * 16 + row16) * 32 + quad * 8];
#pragma unroll
    for (int nt = 0; nt < 2; nt++)
      b[nt] = *(const bf16x8*)&Ws[(wn * 32 + nt * 16 + row16) * 32 + quad * 8];
#pragma unroll
    for (int mt = 0; mt < 4; mt++)
#pragma unroll
      for (int nt = 0; nt < 2; nt++)
        acc[mt][nt] = __builtin_amdgcn_mfma_f32_16x16x32_bf16(a[mt], b[nt], acc[mt][nt], 0, 0, 0);
  }

  __syncthreads();
  // C/D layout: col = lane&15 (+16*nt), row = quad*4 + r (+16*mt)
#pragma unroll
  for (int mt = 0; mt < 4; mt++)
#pragma unroll
    for (int nt = 0; nt < 2; nt++)
#pragma unroll
      for (int r = 0; r < 4; r++)
        CsB[(wm * 64 + mt * 16 + quad * 4 + r) * 72 + wn * 32 + nt * 16 + row16] =
            f2bf(acc[mt][nt][r]);
  __syncthreads();

  if (do_softmax) {
    for (int r = 0; r < 32; r++) {
      const int row = wid * 32 + r;
      float v = bf2f(CsB[row * 72 + lane]);
      float m = v;
#pragma unroll
      for (int o = 32; o > 0; o >>= 1) m = fmaxf(m, __shfl_xor(m, o, 64));
      const float e = __expf(v - m);
      float s = e;
#pragma unroll
      for (int o = 32; o > 0; o >>= 1) s += __shfl_xor(s, o, 64);
      CsB[row * 72 + lane] = f2bf(e / s);
    }
    __syncthreads();
  }

  // coalesced bf16 stores: 1024 x 16B chunks, 2 per thread... (128 rows x 8)
#pragma unroll
  for (int it = 0; it < 2; it++) {
    const int ch = tid + it * 256;        // 0..511
    const int row = ch >> 3, ic = ch & 7; // wait: 512 chunks != 1024
    // 128 rows * 8 chunks = 1024; do 4 per thread instead
    (void)row; (void)ic;
  }
#pragma unroll
  for (int it = 0; it < 4; it++) {
    const int ch = tid + it * 256;        // 0..1023
    const int row = ch >> 3, ic = ch & 7;
    const uint4 val = *(const uint4*)&CsB[row * 72 + ic * 8];
    *(uint4*)&C[(size_t)(bm + row) * DIM + bn + ic * 8] = val;
  }
}

// ------- pass A: T_c[j][i] = sum_t V[t][j] K[t][i]  (MFMA, fp32 out) --------
__global__ __launch_bounds__(256) void chunk_T(const ushort_t* __restrict__ kp,
                                               const ushort_t* __restrict__ vp,
                                               float* __restrict__ cs) {
  __shared__ unsigned int KT[64 * 33];
  __shared__ unsigned int VT[64 * 33];
  const int c = blockIdx.x, h = blockIdx.y, n = blockIdx.z;
  const int tid = threadIdx.x;
  const size_t gbase = ((size_t)(n * LSEQ + c * CS)) * DIM + h * DH;

  transpose_tile(kp + gbase, KT, tid);
  transpose_tile(vp + gbase, VT, tid);
  __syncthreads();

  const int lane = tid & 63, wid = tid >> 6;
  const int row16 = lane & 15, quad = lane >> 4;

  floatx4 acc[4] = {};
#pragma unroll
  for (int ks = 0; ks < 2; ks++) {
    const bf16x8 a = tfrag(VT, wid * 16 + row16, ks * 16 + quad * 4);
#pragma unroll
    for (int nt = 0; nt < 4; nt++) {
      const bf16x8 b = tfrag(KT, nt * 16 + row16, ks * 16 + quad * 4);
      acc[nt] = __builtin_amdgcn_mfma_f32_16x16x32_bf16(a, b, acc[nt], 0, 0, 0);
    }
  }
  float* outp = cs + ((size_t)((n * H + h) * NC + c)) * (DH * DH);
#pragma unroll
  for (int nt = 0; nt < 4; nt++)
#pragma unroll
    for (int r = 0; r < 4; r++)
      outp[(wid * 16 + quad * 4 + r) * DH + nt * 16 + row16] = acc[nt][r];
}

// ------- pass B: exclusive prefix over chunks (fp32 scan -> bf16 out) -------
__global__ __launch_bounds__(256) void prefix_chunks(const float* __restrict__ cs,
                                                     ushort_t* __restrict__ csb) {
  const int nh = blockIdx.x >> 4;
  const int e  = (blockIdx.x & 15) * 256 + threadIdx.x;   // 0..4095
  const float* bf_ = cs + (size_t)nh * NC * (DH * DH) + e;
  ushort_t* bb = csb + (size_t)nh * NC * (DH * DH) + e;
  float run = 0.f;
#pragma unroll
  for (int c = 0; c < NC; c++) {
    const float cur = bf_[(size_t)c * (DH * DH)];
    bb[(size_t)c * (DH * DH)] = f2bf(run);
    run += cur;
  }
}

// ---- pass C: out = Q @ Tpre^T + tril(Q K^T) @ V  (MFMA, fp32 out) ----------
__global__ __launch_bounds__(256) void attn_mfma(const ushort_t* __restrict__ qp,
                                                 const ushort_t* __restrict__ kp,
                                                 const ushort_t* __restrict__ vp,
                                                 const ushort_t* __restrict__ csb,
                                                 float* __restrict__ out) {
  __shared__ ushort_t Qs[64 * 72];
  __shared__ ushort_t Ks[64 * 72];
  __shared__ ushort_t Ts[64 * 72];
  __shared__ unsigned int VT[64 * 33];
  __shared__ ushort_t Pb[64 * 72];
  const int c = blockIdx.x, h = blockIdx.y, n = blockIdx.z;
  const int tid = threadIdx.x;
  const size_t gbase = ((size_t)(n * LSEQ + c * CS)) * DIM + h * DH;
  const size_t cbase = ((size_t)((n * H + h) * NC + c)) * (DH * DH);

  // natural padded staging: 512 chunks of 16B each for Q, K, T -> 2/thread
#pragma unroll
  for (int it = 0; it < 2; it++) {
    const int ch = tid + it * 256;        // 0..511
    const int row = ch >> 3, ic = ch & 7;
    *(uint4*)&Qs[row * 72 + ic * 8] = *(const uint4*)&qp[gbase + (size_t)row * DIM + ic * 8];
    *(uint4*)&Ks[row * 72 + ic * 8] = *(const uint4*)&kp[gbase + (size_t)row * DIM + ic * 8];
    *(uint4*)&Ts[row * 72 + ic * 8] = *(const uint4*)&csb[cbase + (size_t)row * DH + ic * 8];
  }
  transpose_tile(vp + gbase, VT, tid);
  __syncthreads();

  const int lane = tid & 63, wid = tid >> 6;
  const int row16 = lane & 15, quad = lane >> 4;
  const int t0 = wid * 16;

  floatx4 acc[4] = {};    // out rows t0..t0+16, all 64 cols
  floatx4 pacc[4] = {};   // P rows t0..t0+16, all 64 cols

#pragma unroll
  for (int ks = 0; ks < 2; ks++) {
    const bf16x8 aq = *(const bf16x8*)&Qs[(t0 + row16) * 72 + ks * 32 + quad * 8];
#pragma unroll
    for (int nt = 0; nt < 4; nt++) {
      const bf16x8 bt = *(const bf16x8*)&Ts[(nt * 16 + row16) * 72 + ks * 32 + quad * 8];
      acc[nt] = __builtin_amdgcn_mfma_f32_16x16x32_bf16(aq, bt, acc[nt], 0, 0, 0);
      const bf16x8 bk = *(const bf16x8*)&Ks[(nt * 16 + row16) * 72 + ks * 32 + quad * 8];
      pacc[nt] = __builtin_amdgcn_mfma_f32_16x16x32_bf16(aq, bk, pacc[nt], 0, 0, 0);
    }
  }
  // mask P to s<=t, write bf16 to Pb (A-operand natural layout [t][s])
#pragma unroll
  for (int nt = 0; nt < 4; nt++)
#pragma unroll
    for (int r = 0; r < 4; r++) {
      const int t = t0 + quad * 4 + r, s = nt * 16 + row16;
      Pb[t * 72 + s] = f2bf((s <= t) ? pacc[nt][r] : 0.f);
    }
  __syncthreads();

#pragma unroll
  for (int ks = 0; ks < 2; ks++) {
    const bf16x8 ap = *(const bf16x8*)&Pb[(t0 + row16) * 72 + ks * 32 + quad * 8];
#pragma unroll
    for (int nt = 0; nt < 4; nt++) {
      const bf16x8 bv = tfrag(VT, nt * 16 + row16, ks * 16 + quad * 4);
      acc[nt] = __builtin_amdgcn_mfma_f32_16x16x32_bf16(ap, bv, acc[nt], 0, 0, 0);
    }
  }

#pragma unroll
  for (int nt = 0; nt < 4; nt++)
#pragma unroll
    for (int r = 0; r < 4; r++)
      out[gbase + (size_t)(t0 + quad * 4 + r) * DIM + nt * 16 + row16] = acc[nt][r];
}

extern "C" void kernel_launch(void* const* d_in, const int* in_sizes, int n_in,
                              void* d_out, int out_size, void* d_ws, size_t ws_size,
                              hipStream_t stream) {
  const float* query = (const float*)d_in[0];
  const float* key   = (const float*)d_in[1];
  const float* Wq    = (const float*)d_in[2];
  const float* Wk    = (const float*)d_in[3];
  const float* Wv    = (const float*)d_in[4];
  float* out = (float*)d_out;

  // d_ws: [qp 8MB bf16][kp 8MB][vp 8MB][cs 16MB f32][csb 8MB bf16] = 48MB
  // xbf (16MB) overlays cs; wbf (6MB) overlays d_out (dead until attn_mfma)
  const size_t PM = (size_t)4 << 20;                 // 4M elements
  ushort_t* qp = (ushort_t*)d_ws;
  ushort_t* kp = qp + PM;
  ushort_t* vp = kp + PM;
  float*    cs = (float*)(vp + PM);
  ushort_t* csb = (ushort_t*)(cs + PM);
  ushort_t* xbf = (ushort_t*)cs;
  ushort_t* wbf = (ushort_t*)out;

  cast_all<<<dim3(512, 5), 256, 0, stream>>>(query, key, Wq, Wk, Wv, xbf, wbf);

  const dim3 ggrid(DIM / 64, MTOK / 128);            // (16, 32) = 512 blocks
  gemm_bf16<<<ggrid, 256, 0, stream>>>(xbf,              wbf,             qp, 1);
  gemm_bf16<<<ggrid, 256, 0, stream>>>(xbf + (4 << 20),  wbf + (1 << 20), kp, 1);
  gemm_bf16<<<ggrid, 256, 0, stream>>>(xbf + (4 << 20),  wbf + (2 << 20), vp, 0);

  chunk_T<<<dim3(NC, H, NB), 256, 0, stream>>>(kp, vp, cs);
  prefix_chunks<<<dim3(NB * H * 16), 256, 0, stream>>>(cs, csb);
  attn_mfma<<<dim3(NC, H, NB), 256, 0, stream>>>(qp, kp, vp, csb, out);
}

// Round 5
// 172.472 us; speedup vs baseline: 3.4740x; 1.1946x over previous
//
#include <hip/hip_runtime.h>

// Causal linear attention (chunked scan), bf16 MFMA end-to-end.
// q = softmax(x Wq^T), k = softmax(x Wk^T), v = x Wv^T   (one fused MFMA GEMM)
// T_c = sum_{t in chunk} v_t^T (x) k_t  (= S_c^T)        (MFMA, pass A)
// Tpre = exclusive prefix of T_c over chunks (fp32 scan -> bf16)  (pass B)
// out = Q @ Tpre^T + tril(Q K^T) @ V                     (MFMA, pass C)

constexpr int DIM  = 1024;
constexpr int H    = 16;
constexpr int DH   = 64;
constexpr int LSEQ = 2048;
constexpr int NB   = 2;
constexpr int MTOK = NB * LSEQ;   // 4096 tokens
constexpr int CS   = 64;          // chunk size
constexpr int NC   = LSEQ / CS;   // 32 chunks

typedef __bf16 bf16x8 __attribute__((ext_vector_type(8)));
typedef float floatx4 __attribute__((ext_vector_type(4)));
typedef unsigned short ushort_t;

__device__ __forceinline__ ushort_t f2bf(float f) {
  unsigned int u = __float_as_uint(f);
  u += 0x7FFFu + ((u >> 16) & 1u);   // RTNE
  return (ushort_t)(u >> 16);
}
__device__ __forceinline__ float bf2f(ushort_t b) {
  return __uint_as_float(((unsigned int)b) << 16);
}

__device__ __forceinline__ void async16(void* lds, const void* g) {
  __builtin_amdgcn_global_load_lds(
      (const __attribute__((address_space(1))) unsigned int*)g,
      (__attribute__((address_space(3))) unsigned int*)lds, 16, 0, 0);
}

// read a bf16x8 fragment from a transposed stride-33-uint LDS array
__device__ __forceinline__ bf16x8 tfrag(const unsigned int* T, int row, int uoff) {
  union { bf16x8 v; unsigned int u[4]; } r;
  const unsigned int* p = T + row * 33 + uoff;
  r.u[0] = p[0]; r.u[1] = p[1]; r.u[2] = p[2]; r.u[3] = p[3];
  return r.v;
}

// transpose a 64x64 bf16 tile (global, row stride DIM) into stride-33-uint LDS
__device__ __forceinline__ void transpose_tile(const ushort_t* g, unsigned int* TT, int tid) {
  const int ic = tid & 7, tp = tid >> 3;       // tp 0..31, ic 0..7
  const ushort_t* r0 = g + (size_t)(2 * tp) * DIM + ic * 8;
  union { uint4 q; ushort_t u[8]; } a0, a1;
  a0.q = *(const uint4*)r0;
  a1.q = *(const uint4*)(r0 + DIM);
#pragma unroll
  for (int j = 0; j < 8; j++)
    TT[(8 * ic + j) * 33 + tp] = (unsigned int)a0.u[j] | ((unsigned int)a1.u[j] << 16);
}

// ------------- cast fp32 -> bf16 for query/key and the three weights --------
__global__ __launch_bounds__(256) void cast_all(const float* __restrict__ q,
                                                const float* __restrict__ k,
                                                const float* __restrict__ wq,
                                                const float* __restrict__ wk,
                                                const float* __restrict__ wv,
                                                ushort_t* __restrict__ xbf,
                                                ushort_t* __restrict__ wbf) {
  const int seg = blockIdx.y;
  const float* src;
  ushort_t* dst;
  int n4;
  if (seg == 0)      { src = q;  dst = xbf;                  n4 = (4 << 20) / 4; }
  else if (seg == 1) { src = k;  dst = xbf + (4 << 20);      n4 = (4 << 20) / 4; }
  else if (seg == 2) { src = wq; dst = wbf;                  n4 = (1 << 20) / 4; }
  else if (seg == 3) { src = wk; dst = wbf + (1 << 20);      n4 = (1 << 20) / 4; }
  else               { src = wv; dst = wbf + (2 << 20);      n4 = (1 << 20) / 4; }
  for (int i = blockIdx.x * 256 + threadIdx.x; i < n4; i += gridDim.x * 256) {
    const float4 f = ((const float4*)src)[i];
    ((ushort4*)dst)[i] = make_ushort4(f2bf(f.x), f2bf(f.y), f2bf(f.z), f2bf(f.w));
  }
}

// ----- fused bf16 MFMA GEMM NT: z in {0:q,1:k,2:v}, tile 128x128, BK=32 -----
// 4 waves in 2x2; each wave 64x64 (4x4 MFMA / K-iter). In-register per-head
// softmax epilogue for z<2 (wave's 64 cols == one head).
struct Stage { ushort_t As[128 * 32]; ushort_t Ws[128 * 32]; };
union SMemU { Stage st; ushort_t CsB[128 * 136]; };

__global__ __launch_bounds__(256) void gemm_fused(const ushort_t* __restrict__ xbf,
                                                  const ushort_t* __restrict__ wbf,
                                                  ushort_t* __restrict__ qp,
                                                  ushort_t* __restrict__ kp,
                                                  ushort_t* __restrict__ vp) {
  __shared__ SMemU sm;
  const int tid  = threadIdx.x;
  const int z    = blockIdx.z;
  const ushort_t* A = xbf + (z ? (size_t)(4 << 20) : 0);
  const ushort_t* W = wbf + (size_t)z * (1 << 20);
  ushort_t* C = (z == 0) ? qp : ((z == 1) ? kp : vp);
  const int bn   = blockIdx.x * 128;
  const int bm   = blockIdx.y * 128;
  const int lane = tid & 63;
  const int wid  = tid >> 6;
  const int wm   = wid >> 1, wn = wid & 1;
  const int row16 = lane & 15, quad = lane >> 4;

  floatx4 acc[4][4] = {};

  const ushort_t* gA0 = A + (size_t)(bm + (tid >> 2)) * DIM + (tid & 3) * 8;
  const ushort_t* gA1 = A + (size_t)(bm + 64 + (tid >> 2)) * DIM + (tid & 3) * 8;
  const ushort_t* gW0 = W + (size_t)(bn + (tid >> 2)) * DIM + (tid & 3) * 8;
  const ushort_t* gW1 = W + (size_t)(bn + 64 + (tid >> 2)) * DIM + (tid & 3) * 8;
  ushort_t* lA0 = sm.st.As + tid * 8;
  ushort_t* lA1 = sm.st.As + (tid + 256) * 8;
  ushort_t* lW0 = sm.st.Ws + tid * 8;
  ushort_t* lW1 = sm.st.Ws + (tid + 256) * 8;

  for (int k0 = 0; k0 < DIM; k0 += 32) {
    __syncthreads();
    async16(lA0, gA0 + k0);
    async16(lA1, gA1 + k0);
    async16(lW0, gW0 + k0);
    async16(lW1, gW1 + k0);
    __syncthreads();
    bf16x8 a[4], b[4];
#pragma unroll
    for (int mt = 0; mt < 4; mt++)
      a[mt] = *(const bf16x8*)&sm.st.As[(wm * 64 + mt * 16 + row16) * 32 + quad * 8];
#pragma unroll
    for (int nt = 0; nt < 4; nt++)
      b[nt] = *(const bf16x8*)&sm.st.Ws[(wn * 64 + nt * 16 + row16) * 32 + quad * 8];
#pragma unroll
    for (int mt = 0; mt < 4; mt++)
#pragma unroll
      for (int nt = 0; nt < 4; nt++)
        acc[mt][nt] = __builtin_amdgcn_mfma_f32_16x16x32_bf16(a[mt], b[nt], acc[mt][nt], 0, 0, 0);
  }
  __syncthreads();   // all ds_reads done before LDS reuse as CsB

  if (z < 2) {
    // in-register per-head softmax: row (mt,quad,r) spans nt regs x 16 lanes
#pragma unroll
    for (int mt = 0; mt < 4; mt++)
#pragma unroll
      for (int r = 0; r < 4; r++) {
        float m = fmaxf(fmaxf(acc[mt][0][r], acc[mt][1][r]),
                        fmaxf(acc[mt][2][r], acc[mt][3][r]));
#pragma unroll
        for (int o = 1; o < 16; o <<= 1) m = fmaxf(m, __shfl_xor(m, o, 64));
        float e[4], s = 0.f;
#pragma unroll
        for (int nt = 0; nt < 4; nt++) { e[nt] = __expf(acc[mt][nt][r] - m); s += e[nt]; }
#pragma unroll
        for (int o = 1; o < 16; o <<= 1) s += __shfl_xor(s, o, 64);
        const float inv = 1.f / s;
#pragma unroll
        for (int nt = 0; nt < 4; nt++) acc[mt][nt][r] = e[nt] * inv;
      }
  }

  // repack to bf16 in LDS (stride 136), then coalesced 16B stores
#pragma unroll
  for (int mt = 0; mt < 4; mt++)
#pragma unroll
    for (int nt = 0; nt < 4; nt++)
#pragma unroll
      for (int r = 0; r < 4; r++)
        sm.CsB[(wm * 64 + mt * 16 + quad * 4 + r) * 136 + wn * 64 + nt * 16 + row16] =
            f2bf(acc[mt][nt][r]);
  __syncthreads();
#pragma unroll
  for (int it = 0; it < 8; it++) {
    const int ch = tid + it * 256;        // 0..2047 = 128 rows x 16 chunks
    const int row = ch >> 4, ic = ch & 15;
    const uint4 val = *(const uint4*)&sm.CsB[row * 136 + ic * 8];
    *(uint4*)&C[(size_t)(bm + row) * DIM + bn + ic * 8] = val;
  }
}

// ------- pass A: T_c[j][i] = sum_t V[t][j] K[t][i]  (MFMA, fp32 out) --------
__global__ __launch_bounds__(256) void chunk_T(const ushort_t* __restrict__ kp,
                                               const ushort_t* __restrict__ vp,
                                               float* __restrict__ cs) {
  __shared__ unsigned int KT[64 * 33];
  __shared__ unsigned int VT[64 * 33];
  const int c = blockIdx.x, h = blockIdx.y, n = blockIdx.z;
  const int tid = threadIdx.x;
  const size_t gbase = ((size_t)(n * LSEQ + c * CS)) * DIM + h * DH;

  transpose_tile(kp + gbase, KT, tid);
  transpose_tile(vp + gbase, VT, tid);
  __syncthreads();

  const int lane = tid & 63, wid = tid >> 6;
  const int row16 = lane & 15, quad = lane >> 4;

  floatx4 acc[4] = {};
#pragma unroll
  for (int ks = 0; ks < 2; ks++) {
    const bf16x8 a = tfrag(VT, wid * 16 + row16, ks * 16 + quad * 4);
#pragma unroll
    for (int nt = 0; nt < 4; nt++) {
      const bf16x8 b = tfrag(KT, nt * 16 + row16, ks * 16 + quad * 4);
      acc[nt] = __builtin_amdgcn_mfma_f32_16x16x32_bf16(a, b, acc[nt], 0, 0, 0);
    }
  }
  float* outp = cs + ((size_t)((n * H + h) * NC + c)) * (DH * DH);
#pragma unroll
  for (int nt = 0; nt < 4; nt++)
#pragma unroll
    for (int r = 0; r < 4; r++)
      outp[(wid * 16 + quad * 4 + r) * DH + nt * 16 + row16] = acc[nt][r];
}

// ------- pass B: exclusive prefix over chunks (fp32 scan -> bf16 out) -------
__global__ __launch_bounds__(256) void prefix_chunks(const float* __restrict__ cs,
                                                     ushort_t* __restrict__ csb) {
  const int nh = blockIdx.x >> 4;
  const int e  = (blockIdx.x & 15) * 256 + threadIdx.x;   // 0..4095
  const float* bf_ = cs + (size_t)nh * NC * (DH * DH) + e;
  ushort_t* bb = csb + (size_t)nh * NC * (DH * DH) + e;
  float run = 0.f;
#pragma unroll
  for (int c = 0; c < NC; c++) {
    const float cur = bf_[(size_t)c * (DH * DH)];
    bb[(size_t)c * (DH * DH)] = f2bf(run);
    run += cur;
  }
}

// ---- pass C: out = Q @ Tpre^T + tril(Q K^T) @ V  (MFMA, fp32 out) ----------
__global__ __launch_bounds__(256) void attn_mfma(const ushort_t* __restrict__ qp,
                                                 const ushort_t* __restrict__ kp,
                                                 const ushort_t* __restrict__ vp,
                                                 const ushort_t* __restrict__ csb,
                                                 float* __restrict__ out) {
  __shared__ ushort_t Qs[64 * 72];
  __shared__ ushort_t Ks[64 * 72];
  __shared__ ushort_t Ts[64 * 72];
  __shared__ unsigned int VT[64 * 33];
  __shared__ ushort_t Pb[64 * 72];
  const int c = blockIdx.x, h = blockIdx.y, n = blockIdx.z;
  const int tid = threadIdx.x;
  const size_t gbase = ((size_t)(n * LSEQ + c * CS)) * DIM + h * DH;
  const size_t cbase = ((size_t)((n * H + h) * NC + c)) * (DH * DH);

#pragma unroll
  for (int it = 0; it < 2; it++) {
    const int ch = tid + it * 256;        // 0..511
    const int row = ch >> 3, ic = ch & 7;
    *(uint4*)&Qs[row * 72 + ic * 8] = *(const uint4*)&qp[gbase + (size_t)row * DIM + ic * 8];
    *(uint4*)&Ks[row * 72 + ic * 8] = *(const uint4*)&kp[gbase + (size_t)row * DIM + ic * 8];
    *(uint4*)&Ts[row * 72 + ic * 8] = *(const uint4*)&csb[cbase + (size_t)row * DH + ic * 8];
  }
  transpose_tile(vp + gbase, VT, tid);
  __syncthreads();

  const int lane = tid & 63, wid = tid >> 6;
  const int row16 = lane & 15, quad = lane >> 4;
  const int t0 = wid * 16;

  floatx4 acc[4] = {};
  floatx4 pacc[4] = {};

#pragma unroll
  for (int ks = 0; ks < 2; ks++) {
    const bf16x8 aq = *(const bf16x8*)&Qs[(t0 + row16) * 72 + ks * 32 + quad * 8];
#pragma unroll
    for (int nt = 0; nt < 4; nt++) {
      const bf16x8 bt = *(const bf16x8*)&Ts[(nt * 16 + row16) * 72 + ks * 32 + quad * 8];
      acc[nt] = __builtin_amdgcn_mfma_f32_16x16x32_bf16(aq, bt, acc[nt], 0, 0, 0);
      const bf16x8 bk = *(const bf16x8*)&Ks[(nt * 16 + row16) * 72 + ks * 32 + quad * 8];
      pacc[nt] = __builtin_amdgcn_mfma_f32_16x16x32_bf16(aq, bk, pacc[nt], 0, 0, 0);
    }
  }
#pragma unroll
  for (int nt = 0; nt < 4; nt++)
#pragma unroll
    for (int r = 0; r < 4; r++) {
      const int t = t0 + quad * 4 + r, s = nt * 16 + row16;
      Pb[t * 72 + s] = f2bf((s <= t) ? pacc[nt][r] : 0.f);
    }
  __syncthreads();

#pragma unroll
  for (int ks = 0; ks < 2; ks++) {
    const bf16x8 ap = *(const bf16x8*)&Pb[(t0 + row16) * 72 + ks * 32 + quad * 8];
#pragma unroll
    for (int nt = 0; nt < 4; nt++) {
      const bf16x8 bv = tfrag(VT, nt * 16 + row16, ks * 16 + quad * 4);
      acc[nt] = __builtin_amdgcn_mfma_f32_16x16x32_bf16(ap, bv, acc[nt], 0, 0, 0);
    }
  }

#pragma unroll
  for (int nt = 0; nt < 4; nt++)
#pragma unroll
    for (int r = 0; r < 4; r++)
      out[gbase + (size_t)(t0 + quad * 4 + r) * DIM + nt * 16 + row16] = acc[nt][r];
}

extern "C" void kernel_launch(void* const* d_in, const int* in_sizes, int n_in,
                              void* d_out, int out_size, void* d_ws, size_t ws_size,
                              hipStream_t stream) {
  const float* query = (const float*)d_in[0];
  const float* key   = (const float*)d_in[1];
  const float* Wq    = (const float*)d_in[2];
  const float* Wk    = (const float*)d_in[3];
  const float* Wv    = (const float*)d_in[4];
  float* out = (float*)d_out;

  // d_ws: [qp 8MB bf16][kp 8MB][vp 8MB][cs 16MB f32][csb 8MB bf16] = 48MB
  // xbf (16MB) overlays cs; wbf (6MB) overlays d_out (dead until attn_mfma)
  const size_t PM = (size_t)4 << 20;                 // 4M elements
  ushort_t* qp = (ushort_t*)d_ws;
  ushort_t* kp = qp + PM;
  ushort_t* vp = kp + PM;
  float*    cs = (float*)(vp + PM);
  ushort_t* csb = (ushort_t*)(cs + PM);
  ushort_t* xbf = (ushort_t*)cs;
  ushort_t* wbf = (ushort_t*)out;

  cast_all<<<dim3(512, 5), 256, 0, stream>>>(query, key, Wq, Wk, Wv, xbf, wbf);

  gemm_fused<<<dim3(DIM / 128, MTOK / 128, 3), 256, 0, stream>>>(xbf, wbf, qp, kp, vp);

  chunk_T<<<dim3(NC, H, NB), 256, 0, stream>>>(kp, vp, cs);
  prefix_chunks<<<dim3(NB * H * 16), 256, 0, stream>>>(cs, csb);
  attn_mfma<<<dim3(NC, H, NB), 256, 0, stream>>>(qp, kp, vp, csb, out);
}